// Round 8
// baseline (565.908 us; speedup 1.0000x reference)
//
#include <hip/hip_runtime.h>

typedef short  short8  __attribute__((ext_vector_type(8)));
typedef float  float4v __attribute__((ext_vector_type(4)));

#define DIM      1024
#define HEADS    16
#define HEAD_DIM 64
#define HIDDEN   4096
#define BATCH    16
#define SEQ      577
#define M_ROWS   (BATCH*SEQ)   /* 9232 */
#define NPAD2    640           /* keys padded to 10*64 */
#define QKVLD    3072          /* merged qkv row stride */
#define LOG2E    1.4426950408889634f

static __device__ __forceinline__ unsigned short f2bf(float f) {
  unsigned int u = __float_as_uint(f);
  u += 0x7FFFu + ((u >> 16) & 1u);           // round-to-nearest-even
  return (unsigned short)(u >> 16);
}
// async global->LDS, 16B per lane; LDS dest = wave-uniform base + lane*16
static __device__ __forceinline__ void gload_lds16(const void* g, void* l) {
  __builtin_amdgcn_global_load_lds(
      (const __attribute__((address_space(1))) void*)g,
      (__attribute__((address_space(3))) void*)l, 16, 0, 0);
}
// m204 bijective XCD-chunk transform: consecutive OUTPUT ids land on one XCD
static __device__ __forceinline__ int xcd_chunk(int w, int nwg) {
  int xcd = w & 7, rest = w >> 3;
  int q = nwg >> 3, r = nwg & 7;
  int base = xcd < r ? xcd * (q + 1) : r * (q + 1) + (xcd - r) * q;
  return base + rest;
}

// ------------------------------------------------- fp32 -> bf16 (all weights)
__global__ __launch_bounds__(256) void convert_all_kernel(
    const float* __restrict__ Wq, const float* __restrict__ Wk,
    const float* __restrict__ Wv, const float* __restrict__ Wp,
    const float* __restrict__ W1, const float* __restrict__ W2,
    unsigned short* __restrict__ wqkv, unsigned short* __restrict__ wp,
    unsigned short* __restrict__ w1, unsigned short* __restrict__ w2) {
  const int S = DIM * DIM / 4;               // 262144 float4 units per 1024x1024
  int i = blockIdx.x * 256 + threadIdx.x;    // total 12*S
  const float* src; unsigned short* dst; int rel;
  if (i < 4 * S) {
    if (i < S)        { src = Wq; dst = wqkv;               rel = i; }
    else if (i < 2*S) { src = Wk; dst = wqkv + DIM * DIM;   rel = i - S; }
    else if (i < 3*S) { src = Wv; dst = wqkv + 2*DIM*DIM;   rel = i - 2*S; }
    else              { src = Wp; dst = wp;                 rel = i - 3*S; }
  } else if (i < 8*S) { src = W1; dst = w1;                 rel = i - 4*S; }
  else                { src = W2; dst = w2;                 rel = i - 8*S; }
  float4 v = ((const float4*)src)[rel];
  union { unsigned short s[4]; uint2 u; } p;
  p.s[0] = f2bf(v.x); p.s[1] = f2bf(v.y); p.s[2] = f2bf(v.z); p.s[3] = f2bf(v.w);
  ((uint2*)dst)[rel] = p.u;
}

// ---------------------------------------------------------------- LayerNorm row
__global__ __launch_bounds__(256) void ln_kernel(
    const float* __restrict__ x, const float* __restrict__ g,
    const float* __restrict__ b, unsigned short* __restrict__ out) {
  int row = blockIdx.x, tid = threadIdx.x;
  const float* xr = x + (long long)row * DIM;
  float4 v = *(const float4*)(xr + tid * 4);
  float s1 = v.x + v.y + v.z + v.w;
  float s2 = v.x*v.x + v.y*v.y + v.z*v.z + v.w*v.w;
  #pragma unroll
  for (int o = 32; o; o >>= 1) { s1 += __shfl_xor(s1, o); s2 += __shfl_xor(s2, o); }
  __shared__ float a1[4], a2[4];
  int wid = tid >> 6, lane = tid & 63;
  if (lane == 0) { a1[wid] = s1; a2[wid] = s2; }
  __syncthreads();
  s1 = a1[0] + a1[1] + a1[2] + a1[3];
  s2 = a2[0] + a2[1] + a2[2] + a2[3];
  float mean = s1 * (1.f / DIM);
  float var  = s2 * (1.f / DIM) - mean * mean;
  float rstd = rsqrtf(var + 1e-5f);
  float4 gv = *(const float4*)(g + tid * 4);
  float4 bv = *(const float4*)(b + tid * 4);
  union { unsigned short s[4]; uint2 u; } p;
  p.s[0] = f2bf((v.x - mean) * rstd * gv.x + bv.x);
  p.s[1] = f2bf((v.y - mean) * rstd * gv.y + bv.y);
  p.s[2] = f2bf((v.z - mean) * rstd * gv.z + bv.z);
  p.s[3] = f2bf((v.w - mean) * rstd * gv.w + bv.w);
  *(uint2*)(out + (long long)row * DIM + tid * 4) = p.u;
}

// ---------------------------------------------------------------- V transpose
__global__ __launch_bounds__(256) void transpose_v_kernel(
    const unsigned short* __restrict__ v, unsigned short* __restrict__ vt) {
  int nt0 = blockIdx.x * 64;
  int bh = blockIdx.y;
  int b = bh >> 4, h = bh & 15;
  __shared__ unsigned short T[64][72];       // +8 pad (bank-conflict mitigation)
  int tid = threadIdx.x;
  int r = tid >> 3;          // 0..31
  int c = tid & 7;           // 16B chunk
  #pragma unroll
  for (int p = 0; p < 2; p++) {
    int row = p * 32 + r;
    int n = nt0 + row;
    uint4 val = (uint4){0u, 0u, 0u, 0u};
    if (n < SEQ)
      val = *(const uint4*)(v + ((long long)(b * SEQ + n)) * QKVLD + h * HEAD_DIM + c * 8);
    *(uint4*)&T[row][c * 8] = val;
  }
  __syncthreads();
  #pragma unroll
  for (int p = 0; p < 2; p++) {
    int d = p * 32 + (tid >> 3);             // output row (head dim)
    union { unsigned short s[8]; uint4 u; } o;
    #pragma unroll
    for (int i = 0; i < 8; i++) o.s[i] = T[c * 8 + i][d];
    *(uint4*)(vt + ((long long)bh * HEAD_DIM + d) * NPAD2 + nt0 + c * 8) = o.u;
  }
}

// ---------------------------------------------------------------- flash attention
// R7: no running-max, rowsum via ones-MFMA, kt=9 peeled, Q frags from global.
// R9: counted vmcnt(4), XCD-chunked block id. R14: unchanged (proven).
template <bool MASK>
static __device__ __forceinline__ void attn_tile(
    const unsigned short* Ks, const unsigned short* Vs, unsigned short* Ps,
    const short8 (&af)[2][2], float4v (&oacc)[2][4], float4v (&sumacc)[2],
    int quad, int l16, int wid) {
  const float CE = 0.125f * LOG2E;

  short8 bfr[4][2];
  #pragma unroll
  for (int j = 0; j < 4; j++) {
    int r = j * 16 + l16;
    #pragma unroll
    for (int ks = 0; ks < 2; ks++)
      bfr[j][ks] = *(const short8*)(Ks + r * 64 + ((ks * 4 + quad) ^ (l16 & 7)) * 8);
  }

  float4v sacc[2][4];
  #pragma unroll
  for (int i = 0; i < 2; i++)
    #pragma unroll
    for (int j = 0; j < 4; j++) sacc[i][j] = (float4v){0.f, 0.f, 0.f, 0.f};
  #pragma unroll
  for (int i = 0; i < 2; i++)
    #pragma unroll
    for (int j = 0; j < 4; j++)
      #pragma unroll
      for (int ks = 0; ks < 2; ks++)
        sacc[i][j] = __builtin_amdgcn_mfma_f32_16x16x32_bf16(af[i][ks], bfr[j][ks], sacc[i][j], 0, 0, 0);

  #pragma unroll
  for (int i = 0; i < 2; i++) {
    #pragma unroll
    for (int reg = 0; reg < 4; reg++) {
      int prow = wid * 32 + i * 16 + quad * 4 + reg;
      #pragma unroll
      for (int j = 0; j < 4; j++) {
        float pv;
        if constexpr (MASK) {
          pv = (j == 0 && l16 == 0) ? __builtin_amdgcn_exp2f(sacc[i][j][reg] * CE) : 0.f;
        } else {
          pv = __builtin_amdgcn_exp2f(sacc[i][j][reg] * CE);
        }
        int pcol = j * 16 + l16;
        Ps[prow * 64 + (((pcol >> 3) ^ (prow & 7)) * 8) + (pcol & 7)] = f2bf(pv);
      }
    }
  }

  short8 paf[2][2], vbf[4][2];
  #pragma unroll
  for (int i = 0; i < 2; i++) {
    int r = wid * 32 + i * 16 + l16;
    #pragma unroll
    for (int kk = 0; kk < 2; kk++)
      paf[i][kk] = *(const short8*)(Ps + r * 64 + ((kk * 4 + quad) ^ (l16 & 7)) * 8);
  }
  #pragma unroll
  for (int j = 0; j < 4; j++) {
    int r = j * 16 + l16;
    #pragma unroll
    for (int kk = 0; kk < 2; kk++)
      vbf[j][kk] = *(const short8*)(Vs + r * 64 + ((kk * 4 + quad) ^ (l16 & 7)) * 8);
  }
  const short ov = (short)0x3F80;                // bf16 1.0
  const short8 ones = (short8){ov, ov, ov, ov, ov, ov, ov, ov};
  #pragma unroll
  for (int i = 0; i < 2; i++) {
    #pragma unroll
    for (int kk = 0; kk < 2; kk++) {
      #pragma unroll
      for (int j = 0; j < 4; j++)
        oacc[i][j] = __builtin_amdgcn_mfma_f32_16x16x32_bf16(paf[i][kk], vbf[j][kk], oacc[i][j], 0, 0, 0);
      sumacc[i] = __builtin_amdgcn_mfma_f32_16x16x32_bf16(paf[i][kk], ones, sumacc[i], 0, 0, 0);
    }
  }
}

// grid (5, 256) logical; id XCD-chunked so all 5 q-tiles of a bh share one L2.
__global__ __launch_bounds__(256, 3) void flash_attn_kernel(
    const unsigned short* __restrict__ q,   // qkv base + 0,    ld QKVLD
    const unsigned short* __restrict__ k,   // qkv base + 1024, ld QKVLD
    const unsigned short* __restrict__ vt,  // [bh][64][NPAD2]
    unsigned short* __restrict__ o) {       // [B*577][DIM]
  int w = blockIdx.y * 5 + blockIdx.x;
  int id = xcd_chunk(w, 5 * 256);
  int qt = id % 5;
  int bh = id / 5;
  int b = bh >> 4, h = bh & 15;
  int q0 = qt * 128;
  int tid = threadIdx.x, lane = tid & 63, wid = tid >> 6;
  int quad = lane >> 4, l16 = lane & 15;
  long long rowbase = (long long)b * SEQ;

  __shared__ __align__(16) unsigned short SM[24576];   // 48 KB
  // [Ks0 Vs0][Ks1 Vs1][Ps]: 8192 + 8192 + 8192 ushorts
  unsigned short* Ps = SM + 16384;    // [128][64]

  // hoisted staging pointers (clamp only matters at kt=9; rows <576 otherwise)
  int sr = wid * 16 + (lane >> 3);         // this thread's K-row (p adds 8)
  int scc = (lane & 7) ^ (sr & 7);         // swizzled chunk
  const unsigned short* kbase = k + (rowbase + sr) * QKVLD + h * HEAD_DIM + scc * 8;
  const unsigned short* kbase2 = k + (rowbase + sr + 8) * QKVLD + h * HEAD_DIM + (((lane & 7) ^ ((sr + 8) & 7)) * 8);
  const unsigned short* vbase = vt + ((long long)bh * HEAD_DIM + sr) * NPAD2 + scc * 8;
  const unsigned short* vbase2 = vt + ((long long)bh * HEAD_DIM + sr + 8) * NPAD2 + (((lane & 7) ^ ((sr + 8) & 7)) * 8);

  auto stageKV = [&](int sel, int kt) {
    unsigned short* Ks_ = SM + sel * 8192;
    unsigned short* Vs_ = Ks_ + 4096;
    // K rows kt*64 + sr (+8). Only kt==9 can exceed SEQ-1: clamp via offset.
    long long koff = (long long)kt * 64 * QKVLD;
    long long koff2 = koff;
    if (kt == 9) {                          // rows 576+sr: clamp to 576
      koff  -= (long long)((kt * 64 + sr)     - (SEQ - 1) > 0 ? (kt * 64 + sr)     - (SEQ - 1) : 0) * QKVLD;
      koff2 -= (long long)((kt * 64 + sr + 8) - (SEQ - 1) > 0 ? (kt * 64 + sr + 8) - (SEQ - 1) : 0) * QKVLD;
    }
    gload_lds16(kbase  + koff,  Ks_ + sr * 64 - (lane >> 3) * 64);          // wave-uniform dest base
    gload_lds16(kbase2 + koff2, Ks_ + (sr + 8) * 64 - (lane >> 3) * 64);
    gload_lds16(vbase  + kt * 64, Vs_ + sr * 64 - (lane >> 3) * 64);
    gload_lds16(vbase2 + kt * 64, Vs_ + (sr + 8) * 64 - (lane >> 3) * 64);
  };

  // hoisted Q fragments, straight from global
  short8 af[2][2];
  #pragma unroll
  for (int i = 0; i < 2; i++) {
    int gr = q0 + wid * 32 + i * 16 + l16;
    if (gr > SEQ - 1) gr = SEQ - 1;
    const unsigned short* qr = q + (rowbase + gr) * QKVLD + h * HEAD_DIM;
    #pragma unroll
    for (int ks = 0; ks < 2; ks++)
      af[i][ks] = *(const short8*)(qr + (ks * 4 + quad) * 8);
  }

  float4v oacc[2][4];
  float4v sumacc[2];
  #pragma unroll
  for (int i = 0; i < 2; i++) {
    sumacc[i] = (float4v){0.f, 0.f, 0.f, 0.f};
    #pragma unroll
    for (int j = 0; j < 4; j++) oacc[i][j] = (float4v){0.f, 0.f, 0.f, 0.f};
  }

  stageKV(0, 0);                            // 4 loads in flight

  for (int kt = 0; kt < 10; kt++) {
    int cur = kt & 1;
    if (kt < 9) {
      stageKV(cur ^ 1, kt + 1);             // 4 more; <=8 outstanding
      asm volatile("s_waitcnt vmcnt(4)" ::: "memory");   // tile kt landed; kt+1 flies on
    } else {
      asm volatile("s_waitcnt vmcnt(0)" ::: "memory");
    }
    __builtin_amdgcn_s_barrier();           // all waves' tile-kt data visible
    const unsigned short* Ks_ = SM + cur * 8192;
    const unsigned short* Vs_ = Ks_ + 4096;
    if (kt < 9) attn_tile<false>(Ks_, Vs_, Ps, af, oacc, sumacc, quad, l16, wid);
    else        attn_tile<true >(Ks_, Vs_, Ps, af, oacc, sumacc, quad, l16, wid);
    asm volatile("" ::: "memory");
    __builtin_amdgcn_s_barrier();           // done reading bufs before overwrite
  }

  #pragma unroll
  for (int i = 0; i < 2; i++) {
    #pragma unroll
    for (int reg = 0; reg < 4; reg++) {
      int grow = q0 + wid * 32 + i * 16 + quad * 4 + reg;
      if (grow >= SEQ) continue;
      float inv = 1.f / sumacc[i][reg];
      #pragma unroll
      for (int j = 0; j < 4; j++) {
        int d = j * 16 + l16;
        o[(rowbase + grow) * DIM + h * HEAD_DIM + d] = f2bf(oacc[i][j][reg] * inv);
      }
    }
  }
}

// ---------------------------------------------------------------- NT GEMM
// R11-13: K-slice pipeline, 256x256 tile, 8 waves, 4-region ring, lead 3.
// R13 fixed bank conflicts (295K, conflict-free). R14 fixes the remaining
// per-phase serialization (observed 4250 cyc/phase vs ~1150 pipe floor):
// m201's latency-hiding order -- ds_read ISSUES at phase top (before the
// barrier), lgkmcnt(0) drains AFTER it, so read latency hides under
// stage-issue + vmcnt-wait + barrier rendezvous. Ledger: vmcnt(8) at phase p
// confirms unit p+1 (one phase EARLY), so phase p+1's ds_reads issue with no
// wait. W-A-R: B2 (end of phase) => all waves' ds_reads of unit p retired
// before any wave's stage(p+4) overwrites region p&3. rule#18: sched_barrier
// after lgkmcnt asm keeps MFMAs from hoisting past the drain.
enum { EPI_BF16 = 0, EPI_BIAS_RES_F32 = 2, EPI_BIAS_GELU_BF16 = 3 };

template <int EPI>
__global__ __launch_bounds__(512, 2) void gemm_nt(
    const unsigned short* __restrict__ A, int lda,
    const unsigned short* __restrict__ B, int ldb,
    void* __restrict__ Cout, int ldc,
    const float* __restrict__ bias, const float* __restrict__ res,
    int M, int N, int K) {
  int mt = gridDim.x, nt = gridDim.y;
  int nwg = mt * nt;
  int id = xcd_chunk(blockIdx.y * mt + blockIdx.x, nwg);
  // ---- band swizzle: bands of 8 m-tiles, m fastest within band ----
  int band  = id / (8 * nt);
  int rem   = id - band * 8 * nt;
  int mrem  = mt - band * 8;
  int bandh = mrem < 8 ? mrem : 8;
  int lm = rem % bandh;
  int nb = rem / bandh;
  int m0 = (band * 8 + lm) * 256, n0 = nb * 256;

  int tid = threadIdx.x;
  int lane = tid & 63, wid = tid >> 6;          // 8 waves
  int wm = wid >> 2, wn = wid & 3;              // 2M x 4N
  int quad = lane >> 4, l16 = lane & 15;

  // 4 units x (A 16KB + B 16KB) = 128 KB ring
  __shared__ __align__(16) unsigned short SMB[65536];

  float4v acc[8][4];
  #pragma unroll
  for (int i = 0; i < 8; i++)
    #pragma unroll
    for (int j = 0; j < 4; j++) acc[i][j] = (float4v){0.f, 0.f, 0.f, 0.f};

  // staging: wave wid covers rows wid*32..+31; lane -> row +(lane>>2), chunk lane&3.
  // LDS slot (r, c) holds global chunk c ^ ((r>>1)&3); (lane>>3)&3 = (row_local>>1)&3.
  int srow = wid * 32 + (lane >> 2);
  int sc   = (((lane & 3) ^ ((lane >> 3) & 3))) * 8;   // pre-swizzled src chunk
  const unsigned short* pA[2];
  const unsigned short* pB[2];
  #pragma unroll
  for (int ii = 0; ii < 2; ii++) {
    int gr = m0 + srow + ii * 16; if (gr > M - 1) gr = M - 1;
    pA[ii] = A + (long long)gr * lda + sc;
    int gn = n0 + srow + ii * 16; if (gn > N - 1) gn = N - 1;
    pB[ii] = B + (long long)gn * ldb + sc;
  }

  auto stage = [&](int u) {
    unsigned short* As_ = SMB + (u & 3) * 16384;
    unsigned short* Bs_ = As_ + 8192;
    int k0 = u << 5;
    #pragma unroll
    for (int ii = 0; ii < 2; ii++) {
      int rbase = (wid * 32 + ii * 16) * 32;    // wave-uniform dest (ushorts)
      gload_lds16(pA[ii] + k0, As_ + rbase);
      gload_lds16(pB[ii] + k0, Bs_ + rbase);
    }
  };

  // reader: LDS chunk quad^((l16>>1)&3) holds global chunk quad (K-offset quad*8)
  int rsw = (quad ^ ((l16 >> 1) & 3)) << 3;     // swizzled chunk (ushorts)
  short8 a[8], b[4];
  auto lread = [&](int u) {                     // issue ds_reads (no drain here)
    const unsigned short* As_ = SMB + (u & 3) * 16384;
    const unsigned short* Bs_ = As_ + 8192;
    #pragma unroll
    for (int mi = 0; mi < 8; mi++)
      a[mi] = *(const short8*)(As_ + (wm * 128 + mi * 16 + l16) * 32 + rsw);
    #pragma unroll
    for (int ni = 0; ni < 4; ni++)
      b[ni] = *(const short8*)(Bs_ + (wn * 64 + ni * 16 + l16) * 32 + rsw);
  };
  auto mfma_blk = [&]() {
    __builtin_amdgcn_s_setprio(1);
    #pragma unroll
    for (int mi = 0; mi < 8; mi++)
      #pragma unroll
      for (int ni = 0; ni < 4; ni++)
        acc[mi][ni] = __builtin_amdgcn_mfma_f32_16x16x32_bf16(a[mi], b[ni], acc[mi][ni], 0, 0, 0);
    __builtin_amdgcn_s_setprio(0);
  };

  int U = K >> 5;                               // K-slices of 32 (>=32 always)
  stage(0); stage(1); stage(2);                 // 12 loads in flight
  asm volatile("s_waitcnt vmcnt(8)" ::: "memory");   // unit 0 landed (mine)
  __builtin_amdgcn_s_barrier();                 // unit 0 visible to all waves

  for (int p = 0; p < U - 3; p++) {
    lread(p);                                   // issue reads of unit p (confirmed)
    stage(p + 3);                               // 16 outstanding
    asm volatile("s_waitcnt vmcnt(8)" ::: "memory");  // unit p+1 landed (mine)
    __builtin_amdgcn_s_barrier();               // B1: unit p+1 confirmed for all
    asm volatile("s_waitcnt lgkmcnt(0)" ::: "memory");
    __builtin_amdgcn_sched_barrier(0);          // rule #18
    mfma_blk();
    __builtin_amdgcn_s_barrier();               // B2: reads of unit p retired
  }
  // tail: units U-3, U-2, U-1 (no staging; drain 4 -> 0)
  lread(U - 3);
  asm volatile("s_waitcnt vmcnt(4)" ::: "memory");    // unit U-2 landed
  __builtin_amdgcn_s_barrier();
  asm volatile("s_waitcnt lgkmcnt(0)" ::: "memory");
  __builtin_amdgcn_sched_barrier(0);
  mfma_blk();
  __builtin_amdgcn_s_barrier();
  lread(U - 2);
  asm volatile("s_waitcnt vmcnt(0)" ::: "memory");    // unit U-1 landed
  __builtin_amdgcn_s_barrier();
  asm volatile("s_waitcnt lgkmcnt(0)" ::: "memory");
  __builtin_amdgcn_sched_barrier(0);
  mfma_blk();
  __builtin_amdgcn_s_barrier();
  lread(U - 1);
  asm volatile("s_waitcnt lgkmcnt(0)" ::: "memory");
  __builtin_amdgcn_sched_barrier(0);
  mfma_blk();
  __builtin_amdgcn_s_barrier();                 // all reads retired before epilogue

  // -------- epilogue via LDS (per-wave 16x64 fp32 slab, row stride 68) -----
  float* cs = (float*)SMB + wid * (16 * 68);
  int erow = lane >> 2;
  int eq   = lane & 3;

  #pragma unroll
  for (int mi = 0; mi < 8; mi++) {
    #pragma unroll
    for (int ni = 0; ni < 4; ni++)
      #pragma unroll
      for (int r = 0; r < 4; r++)
        cs[(quad * 4 + r) * 68 + ni * 16 + l16] = acc[mi][ni][r];
    int grow = m0 + wm * 128 + mi * 16 + erow;
    bool rowok = grow < M;

    if constexpr (EPI == EPI_BIAS_RES_F32) {
      #pragma unroll
      for (int t = 0; t < 4; t++) {
        int colb = t * 16 + eq * 4;
        int gcol = n0 + wn * 64 + colb;
        if (!rowok) continue;
        float4 vv = *(const float4*)&cs[erow * 68 + colb];
        float4 bb = *(const float4*)&bias[gcol];
        const float4 rr = *(const float4*)&res[(long long)grow * ldc + gcol];
        vv.x += bb.x + rr.x; vv.y += bb.y + rr.y;
        vv.z += bb.z + rr.z; vv.w += bb.w + rr.w;
        *(float4*)((float*)Cout + (long long)grow * ldc + gcol) = vv;
      }
    } else {
      #pragma unroll
      for (int h = 0; h < 2; h++) {
        int colb = h * 32 + eq * 8;
        int gcol = n0 + wn * 64 + colb;
        if (!rowok) continue;
        float4 a0 = *(const float4*)&cs[erow * 68 + colb];
        float4 a1 = *(const float4*)&cs[erow * 68 + colb + 4];
        float vs[8] = {a0.x, a0.y, a0.z, a0.w, a1.x, a1.y, a1.z, a1.w};
        if constexpr (EPI == EPI_BIAS_GELU_BF16) {
          float4 b0 = *(const float4*)&bias[gcol];
          float4 b1 = *(const float4*)&bias[gcol + 4];
          float bs[8] = {b0.x, b0.y, b0.z, b0.w, b1.x, b1.y, b1.z, b1.w};
          #pragma unroll
          for (int e = 0; e < 8; e++) {
            float tt = vs[e] + bs[e];
            float ex = __builtin_amdgcn_exp2f(tt * -2.4554669595930156f);
            vs[e] = tt / (1.f + ex);
          }
        }
        union { unsigned short s[8]; uint4 u; } p;
        #pragma unroll
        for (int e = 0; e < 8; e++) p.s[e] = f2bf(vs[e]);
        *(uint4*)((unsigned short*)Cout + (long long)grow * ldc + gcol) = p.u;
      }
    }
  }
}

// ----------------------------------------------------------------------------
extern "C" void kernel_launch(void* const* d_in, const int* in_sizes, int n_in,
                              void* d_out, int out_size, void* d_ws, size_t ws_size,
                              hipStream_t stream) {
  const float* x   = (const float*)d_in[0];
  const float* g1  = (const float*)d_in[1];
  const float* be1 = (const float*)d_in[2];
  const float* Wq  = (const float*)d_in[3];
  const float* Wk  = (const float*)d_in[4];
  const float* Wv  = (const float*)d_in[5];
  const float* Wp  = (const float*)d_in[6];
  const float* bp  = (const float*)d_in[7];
  const float* g2  = (const float*)d_in[8];
  const float* be2 = (const float*)d_in[9];
  const float* W1  = (const float*)d_in[10];
  const float* b1  = (const float*)d_in[11];
  const float* W2  = (const float*)d_in[12];
  const float* b2  = (const float*)d_in[13];
  float* out = (float*)d_out;

  char* ws = (char*)d_ws;
  size_t off = 0;
  auto alloc = [&](size_t bytes) {
    size_t r = off; off += (bytes + 255) & ~(size_t)255; return r;
  };
  unsigned short* wqkv_bf = (unsigned short*)(ws + alloc((size_t)3 * DIM * DIM * 2)); // [Wq;Wk;Wv]
  unsigned short* wp_bf   = (unsigned short*)(ws + alloc((size_t)DIM * DIM * 2));
  unsigned short* w1_bf   = (unsigned short*)(ws + alloc((size_t)HIDDEN * DIM * 2));
  unsigned short* w2_bf   = (unsigned short*)(ws + alloc((size_t)HIDDEN * DIM * 2));
  unsigned short* h_bf    = (unsigned short*)(ws + alloc((size_t)M_ROWS * DIM * 2));  // ln1; later o; later ln2
  unsigned short* qkv_bf  = (unsigned short*)(ws + alloc((size_t)M_ROWS * QKVLD * 2));
  unsigned short* vt_bf   = (unsigned short*)(ws + alloc((size_t)256 * HEAD_DIM * NPAD2 * 2));

  unsigned short* o_bf  = h_bf;     // o written after ln1-out dead
  unsigned short* h2_bf = h_bf;     // ln2-out after o consumed
  unsigned short* u_bf  = qkv_bf;   // MLP hidden (75.6 MB) over dead [qkv|vt] span
  float*          x1    = out;      // residual-1 lives in d_out

  // 1. all weights fp32 -> bf16, one launch
  convert_all_kernel<<<12 * (DIM * DIM / 4) / 256, 256, 0, stream>>>(
      Wq, Wk, Wv, Wp, W1, W2, wqkv_bf, wp_bf, w1_bf, w2_bf);

  // 2. h = LN1(x)
  ln_kernel<<<M_ROWS, 256, 0, stream>>>(x, g1, be1, h_bf);

  // 3. qkv = h @ [Wq;Wk;Wv]^T   (one GEMM, N = 3072); 37 = ceil(9232/256)
  gemm_nt<EPI_BF16><<<dim3(37, 12), 512, 0, stream>>>(h_bf, DIM, wqkv_bf, DIM,
      qkv_bf, QKVLD, nullptr, nullptr, M_ROWS, 3 * DIM, DIM);

  // 4. vt[bh][d][n]
  transpose_v_kernel<<<dim3(10, 256), 256, 0, stream>>>(qkv_bf + 2 * DIM, vt_bf);

  // 5. fused flash attention -> o
  flash_attn_kernel<<<dim3(5, 256), 256, 0, stream>>>(
      qkv_bf, qkv_bf + DIM, vt_bf, o_bf);

  // 6. x1 = x + O @ Wp^T + bp   (x1 lives in d_out)
  gemm_nt<EPI_BIAS_RES_F32><<<dim3(37, 4), 512, 0, stream>>>(o_bf, DIM, wp_bf, DIM,
      x1, DIM, bp, x, M_ROWS, DIM, DIM);

  // 7. h2 = LN2(x1)
  ln_kernel<<<M_ROWS, 256, 0, stream>>>(x1, g2, be2, h2_bf);

  // 8. u = fast_gelu(h2 @ W1^T + b1)
  gemm_nt<EPI_BIAS_GELU_BF16><<<dim3(37, 16), 512, 0, stream>>>(h2_bf, DIM, w1_bf, DIM,
      u_bf, HIDDEN, b1, nullptr, M_ROWS, HIDDEN, DIM);

  // 9. out = x1 + u @ W2^T + b2
  gemm_nt<EPI_BIAS_RES_F32><<<dim3(37, 4), 512, 0, stream>>>(u_bf, HIDDEN, w2_bf, HIDDEN,
      out, DIM, b2, x1, M_ROWS, DIM, HIDDEN);
}

// Round 9
// 496.977 us; speedup vs baseline: 1.1387x; 1.1387x over previous
//
#include <hip/hip_runtime.h>

typedef short  short8  __attribute__((ext_vector_type(8)));
typedef float  float4v __attribute__((ext_vector_type(4)));

#define DIM      1024
#define HEADS    16
#define HEAD_DIM 64
#define HIDDEN   4096
#define BATCH    16
#define SEQ      577
#define M_ROWS   (BATCH*SEQ)   /* 9232 */
#define NPAD2    640           /* keys padded to 10*64 */
#define QKVLD    3072          /* merged qkv row stride */
#define LOG2E    1.4426950408889634f

static __device__ __forceinline__ unsigned short f2bf(float f) {
  unsigned int u = __float_as_uint(f);
  u += 0x7FFFu + ((u >> 16) & 1u);           // round-to-nearest-even
  return (unsigned short)(u >> 16);
}
// async global->LDS, 16B per lane; LDS dest = wave-uniform base + lane*16
static __device__ __forceinline__ void gload_lds16(const void* g, void* l) {
  __builtin_amdgcn_global_load_lds(
      (const __attribute__((address_space(1))) void*)g,
      (__attribute__((address_space(3))) void*)l, 16, 0, 0);
}
// m204 bijective XCD-chunk transform: consecutive OUTPUT ids land on one XCD
static __device__ __forceinline__ int xcd_chunk(int w, int nwg) {
  int xcd = w & 7, rest = w >> 3;
  int q = nwg >> 3, r = nwg & 7;
  int base = xcd < r ? xcd * (q + 1) : r * (q + 1) + (xcd - r) * q;
  return base + rest;
}

// ------------------------------------------------- fp32 -> bf16 (all weights)
__global__ __launch_bounds__(256) void convert_all_kernel(
    const float* __restrict__ Wq, const float* __restrict__ Wk,
    const float* __restrict__ Wv, const float* __restrict__ Wp,
    const float* __restrict__ W1, const float* __restrict__ W2,
    unsigned short* __restrict__ wqkv, unsigned short* __restrict__ wp,
    unsigned short* __restrict__ w1, unsigned short* __restrict__ w2) {
  const int S = DIM * DIM / 4;               // 262144 float4 units per 1024x1024
  int i = blockIdx.x * 256 + threadIdx.x;    // total 12*S
  const float* src; unsigned short* dst; int rel;
  if (i < 4 * S) {
    if (i < S)        { src = Wq; dst = wqkv;               rel = i; }
    else if (i < 2*S) { src = Wk; dst = wqkv + DIM * DIM;   rel = i - S; }
    else if (i < 3*S) { src = Wv; dst = wqkv + 2*DIM*DIM;   rel = i - 2*S; }
    else              { src = Wp; dst = wp;                 rel = i - 3*S; }
  } else if (i < 8*S) { src = W1; dst = w1;                 rel = i - 4*S; }
  else                { src = W2; dst = w2;                 rel = i - 8*S; }
  float4 v = ((const float4*)src)[rel];
  union { unsigned short s[4]; uint2 u; } p;
  p.s[0] = f2bf(v.x); p.s[1] = f2bf(v.y); p.s[2] = f2bf(v.z); p.s[3] = f2bf(v.w);
  ((uint2*)dst)[rel] = p.u;
}

// ---------------------------------------------------------------- LayerNorm row
__global__ __launch_bounds__(256) void ln_kernel(
    const float* __restrict__ x, const float* __restrict__ g,
    const float* __restrict__ b, unsigned short* __restrict__ out) {
  int row = blockIdx.x, tid = threadIdx.x;
  const float* xr = x + (long long)row * DIM;
  float4 v = *(const float4*)(xr + tid * 4);
  float s1 = v.x + v.y + v.z + v.w;
  float s2 = v.x*v.x + v.y*v.y + v.z*v.z + v.w*v.w;
  #pragma unroll
  for (int o = 32; o; o >>= 1) { s1 += __shfl_xor(s1, o); s2 += __shfl_xor(s2, o); }
  __shared__ float a1[4], a2[4];
  int wid = tid >> 6, lane = tid & 63;
  if (lane == 0) { a1[wid] = s1; a2[wid] = s2; }
  __syncthreads();
  s1 = a1[0] + a1[1] + a1[2] + a1[3];
  s2 = a2[0] + a2[1] + a2[2] + a2[3];
  float mean = s1 * (1.f / DIM);
  float var  = s2 * (1.f / DIM) - mean * mean;
  float rstd = rsqrtf(var + 1e-5f);
  float4 gv = *(const float4*)(g + tid * 4);
  float4 bv = *(const float4*)(b + tid * 4);
  union { unsigned short s[4]; uint2 u; } p;
  p.s[0] = f2bf((v.x - mean) * rstd * gv.x + bv.x);
  p.s[1] = f2bf((v.y - mean) * rstd * gv.y + bv.y);
  p.s[2] = f2bf((v.z - mean) * rstd * gv.z + bv.z);
  p.s[3] = f2bf((v.w - mean) * rstd * gv.w + bv.w);
  *(uint2*)(out + (long long)row * DIM + tid * 4) = p.u;
}

// ---------------------------------------------------------------- V transpose
__global__ __launch_bounds__(256) void transpose_v_kernel(
    const unsigned short* __restrict__ v, unsigned short* __restrict__ vt) {
  int nt0 = blockIdx.x * 64;
  int bh = blockIdx.y;
  int b = bh >> 4, h = bh & 15;
  __shared__ unsigned short T[64][72];       // +8 pad (bank-conflict mitigation)
  int tid = threadIdx.x;
  int r = tid >> 3;          // 0..31
  int c = tid & 7;           // 16B chunk
  #pragma unroll
  for (int p = 0; p < 2; p++) {
    int row = p * 32 + r;
    int n = nt0 + row;
    uint4 val = (uint4){0u, 0u, 0u, 0u};
    if (n < SEQ)
      val = *(const uint4*)(v + ((long long)(b * SEQ + n)) * QKVLD + h * HEAD_DIM + c * 8);
    *(uint4*)&T[row][c * 8] = val;
  }
  __syncthreads();
  #pragma unroll
  for (int p = 0; p < 2; p++) {
    int d = p * 32 + (tid >> 3);             // output row (head dim)
    union { unsigned short s[8]; uint4 u; } o;
    #pragma unroll
    for (int i = 0; i < 8; i++) o.s[i] = T[c * 8 + i][d];
    *(uint4*)(vt + ((long long)bh * HEAD_DIM + d) * NPAD2 + nt0 + c * 8) = o.u;
  }
}

// ---------------------------------------------------------------- flash attention
// R7: no running-max, rowsum via ones-MFMA, kt=9 peeled, Q frags from global.
// R9: counted vmcnt(4), XCD-chunked block id. R15: unchanged (proven).
template <bool MASK>
static __device__ __forceinline__ void attn_tile(
    const unsigned short* Ks, const unsigned short* Vs, unsigned short* Ps,
    const short8 (&af)[2][2], float4v (&oacc)[2][4], float4v (&sumacc)[2],
    int quad, int l16, int wid) {
  const float CE = 0.125f * LOG2E;

  short8 bfr[4][2];
  #pragma unroll
  for (int j = 0; j < 4; j++) {
    int r = j * 16 + l16;
    #pragma unroll
    for (int ks = 0; ks < 2; ks++)
      bfr[j][ks] = *(const short8*)(Ks + r * 64 + ((ks * 4 + quad) ^ (l16 & 7)) * 8);
  }

  float4v sacc[2][4];
  #pragma unroll
  for (int i = 0; i < 2; i++)
    #pragma unroll
    for (int j = 0; j < 4; j++) sacc[i][j] = (float4v){0.f, 0.f, 0.f, 0.f};
  #pragma unroll
  for (int i = 0; i < 2; i++)
    #pragma unroll
    for (int j = 0; j < 4; j++)
      #pragma unroll
      for (int ks = 0; ks < 2; ks++)
        sacc[i][j] = __builtin_amdgcn_mfma_f32_16x16x32_bf16(af[i][ks], bfr[j][ks], sacc[i][j], 0, 0, 0);

  #pragma unroll
  for (int i = 0; i < 2; i++) {
    #pragma unroll
    for (int reg = 0; reg < 4; reg++) {
      int prow = wid * 32 + i * 16 + quad * 4 + reg;
      #pragma unroll
      for (int j = 0; j < 4; j++) {
        float pv;
        if constexpr (MASK) {
          pv = (j == 0 && l16 == 0) ? __builtin_amdgcn_exp2f(sacc[i][j][reg] * CE) : 0.f;
        } else {
          pv = __builtin_amdgcn_exp2f(sacc[i][j][reg] * CE);
        }
        int pcol = j * 16 + l16;
        Ps[prow * 64 + (((pcol >> 3) ^ (prow & 7)) * 8) + (pcol & 7)] = f2bf(pv);
      }
    }
  }

  short8 paf[2][2], vbf[4][2];
  #pragma unroll
  for (int i = 0; i < 2; i++) {
    int r = wid * 32 + i * 16 + l16;
    #pragma unroll
    for (int kk = 0; kk < 2; kk++)
      paf[i][kk] = *(const short8*)(Ps + r * 64 + ((kk * 4 + quad) ^ (l16 & 7)) * 8);
  }
  #pragma unroll
  for (int j = 0; j < 4; j++) {
    int r = j * 16 + l16;
    #pragma unroll
    for (int kk = 0; kk < 2; kk++)
      vbf[j][kk] = *(const short8*)(Vs + r * 64 + ((kk * 4 + quad) ^ (l16 & 7)) * 8);
  }
  const short ov = (short)0x3F80;                // bf16 1.0
  const short8 ones = (short8){ov, ov, ov, ov, ov, ov, ov, ov};
  #pragma unroll
  for (int i = 0; i < 2; i++) {
    #pragma unroll
    for (int kk = 0; kk < 2; kk++) {
      #pragma unroll
      for (int j = 0; j < 4; j++)
        oacc[i][j] = __builtin_amdgcn_mfma_f32_16x16x32_bf16(paf[i][kk], vbf[j][kk], oacc[i][j], 0, 0, 0);
      sumacc[i] = __builtin_amdgcn_mfma_f32_16x16x32_bf16(paf[i][kk], ones, sumacc[i], 0, 0, 0);
    }
  }
}

// grid (5, 256) logical; id XCD-chunked so all 5 q-tiles of a bh share one L2.
__global__ __launch_bounds__(256, 3) void flash_attn_kernel(
    const unsigned short* __restrict__ q,   // qkv base + 0,    ld QKVLD
    const unsigned short* __restrict__ k,   // qkv base + 1024, ld QKVLD
    const unsigned short* __restrict__ vt,  // [bh][64][NPAD2]
    unsigned short* __restrict__ o) {       // [B*577][DIM]
  int w = blockIdx.y * 5 + blockIdx.x;
  int id = xcd_chunk(w, 5 * 256);
  int qt = id % 5;
  int bh = id / 5;
  int b = bh >> 4, h = bh & 15;
  int q0 = qt * 128;
  int tid = threadIdx.x, lane = tid & 63, wid = tid >> 6;
  int quad = lane >> 4, l16 = lane & 15;
  long long rowbase = (long long)b * SEQ;

  __shared__ __align__(16) unsigned short SM[24576];   // 48 KB
  // [Ks0 Vs0][Ks1 Vs1][Ps]: 8192 + 8192 + 8192 ushorts
  unsigned short* Ps = SM + 16384;    // [128][64]

  // hoisted staging pointers (clamp only matters at kt=9; rows <576 otherwise)
  int sr = wid * 16 + (lane >> 3);         // this thread's K-row (p adds 8)
  int scc = (lane & 7) ^ (sr & 7);         // swizzled chunk
  const unsigned short* kbase = k + (rowbase + sr) * QKVLD + h * HEAD_DIM + scc * 8;
  const unsigned short* kbase2 = k + (rowbase + sr + 8) * QKVLD + h * HEAD_DIM + (((lane & 7) ^ ((sr + 8) & 7)) * 8);
  const unsigned short* vbase = vt + ((long long)bh * HEAD_DIM + sr) * NPAD2 + scc * 8;
  const unsigned short* vbase2 = vt + ((long long)bh * HEAD_DIM + sr + 8) * NPAD2 + (((lane & 7) ^ ((sr + 8) & 7)) * 8);

  auto stageKV = [&](int sel, int kt) {
    unsigned short* Ks_ = SM + sel * 8192;
    unsigned short* Vs_ = Ks_ + 4096;
    // K rows kt*64 + sr (+8). Only kt==9 can exceed SEQ-1: clamp via offset.
    long long koff = (long long)kt * 64 * QKVLD;
    long long koff2 = koff;
    if (kt == 9) {                          // rows 576+sr: clamp to 576
      koff  -= (long long)((kt * 64 + sr)     - (SEQ - 1) > 0 ? (kt * 64 + sr)     - (SEQ - 1) : 0) * QKVLD;
      koff2 -= (long long)((kt * 64 + sr + 8) - (SEQ - 1) > 0 ? (kt * 64 + sr + 8) - (SEQ - 1) : 0) * QKVLD;
    }
    gload_lds16(kbase  + koff,  Ks_ + sr * 64 - (lane >> 3) * 64);          // wave-uniform dest base
    gload_lds16(kbase2 + koff2, Ks_ + (sr + 8) * 64 - (lane >> 3) * 64);
    gload_lds16(vbase  + kt * 64, Vs_ + sr * 64 - (lane >> 3) * 64);
    gload_lds16(vbase2 + kt * 64, Vs_ + (sr + 8) * 64 - (lane >> 3) * 64);
  };

  // hoisted Q fragments, straight from global
  short8 af[2][2];
  #pragma unroll
  for (int i = 0; i < 2; i++) {
    int gr = q0 + wid * 32 + i * 16 + l16;
    if (gr > SEQ - 1) gr = SEQ - 1;
    const unsigned short* qr = q + (rowbase + gr) * QKVLD + h * HEAD_DIM;
    #pragma unroll
    for (int ks = 0; ks < 2; ks++)
      af[i][ks] = *(const short8*)(qr + (ks * 4 + quad) * 8);
  }

  float4v oacc[2][4];
  float4v sumacc[2];
  #pragma unroll
  for (int i = 0; i < 2; i++) {
    sumacc[i] = (float4v){0.f, 0.f, 0.f, 0.f};
    #pragma unroll
    for (int j = 0; j < 4; j++) oacc[i][j] = (float4v){0.f, 0.f, 0.f, 0.f};
  }

  stageKV(0, 0);                            // 4 loads in flight

  for (int kt = 0; kt < 10; kt++) {
    int cur = kt & 1;
    if (kt < 9) {
      stageKV(cur ^ 1, kt + 1);             // 4 more; <=8 outstanding
      asm volatile("s_waitcnt vmcnt(4)" ::: "memory");   // tile kt landed; kt+1 flies on
    } else {
      asm volatile("s_waitcnt vmcnt(0)" ::: "memory");
    }
    __builtin_amdgcn_s_barrier();           // all waves' tile-kt data visible
    const unsigned short* Ks_ = SM + cur * 8192;
    const unsigned short* Vs_ = Ks_ + 4096;
    if (kt < 9) attn_tile<false>(Ks_, Vs_, Ps, af, oacc, sumacc, quad, l16, wid);
    else        attn_tile<true >(Ks_, Vs_, Ps, af, oacc, sumacc, quad, l16, wid);
    asm volatile("" ::: "memory");
    __builtin_amdgcn_s_barrier();           // done reading bufs before overwrite
  }

  #pragma unroll
  for (int i = 0; i < 2; i++) {
    #pragma unroll
    for (int reg = 0; reg < 4; reg++) {
      int grow = q0 + wid * 32 + i * 16 + quad * 4 + reg;
      if (grow >= SEQ) continue;
      float inv = 1.f / sumacc[i][reg];
      #pragma unroll
      for (int j = 0; j < 4; j++) {
        int d = j * 16 + l16;
        o[(rowbase + grow) * DIM + h * HEAD_DIM + d] = f2bf(oacc[i][j][reg] * inv);
      }
    }
  }
}

// ---------------------------------------------------------------- NT GEMM
// R15: REVERT to the R10/m97 single-buffer structure (measured best: 107.5us
// W-GEMM, 64 VGPR, 32 KB LDS, 4-5 blocks/CU). The K-slice deep pipeline
// (R11-R14) never beat it: at 1 block/CU the 2-barrier-per-phase lockstep has
// no cross-block TLP to hide rendezvous (R12 144.5 -> R13 131.4 -> R14 128.2,
// all > 107.5). m97 at high occupancy wins via implicit wave-level overlap
// (m99/m100). Kept: XCD-chunk, band swizzle, hoisted staging pointers,
// XOR-chunk LDS swizzle (conflict-free), launch_bounds(256,4).
enum { EPI_BF16 = 0, EPI_BIAS_RES_F32 = 2, EPI_BIAS_GELU_BF16 = 3 };

template <int EPI>
__global__ __launch_bounds__(256, 4) void gemm_nt(
    const unsigned short* __restrict__ A, int lda,
    const unsigned short* __restrict__ B, int ldb,
    void* __restrict__ Cout, int ldc,
    const float* __restrict__ bias, const float* __restrict__ res,
    int M, int N, int K) {
  int mt = gridDim.x, nt = gridDim.y;
  int nwg = mt * nt;
  int id = xcd_chunk(blockIdx.y * mt + blockIdx.x, nwg);
  // ---- band swizzle: bands of 8 m-tiles, m fastest within band ----
  int band  = id / (8 * nt);
  int rem   = id - band * 8 * nt;
  int mrem  = mt - band * 8;
  int bandh = mrem < 8 ? mrem : 8;
  int lm = rem % bandh;
  int nb = rem / bandh;
  int m0 = (band * 8 + lm) * 128, n0 = nb * 128;

  int tid = threadIdx.x;
  int lane = tid & 63, wid = tid >> 6;
  int wm = wid >> 1, wn = wid & 1;
  int quad = lane >> 4, l16 = lane & 15;

  // single K-tile buffer: As[128][64] + Bs[128][64] = 32768 B;
  // epilogue slab 17408 B reuses it
  __shared__ __align__(16) char SMEM[32768];
  unsigned short* As = (unsigned short*)SMEM;        // XOR-chunk swizzled
  unsigned short* Bs = As + 128 * 64;

  float4v acc[4][4];
  #pragma unroll
  for (int i = 0; i < 4; i++)
    #pragma unroll
    for (int j = 0; j < 4; j++) acc[i][j] = (float4v){0.f, 0.f, 0.f, 0.f};

  int lr8 = lane >> 3;                 // 0..7 row within 8-row group
  int sc  = ((lane & 7) ^ lr8) * 8;    // swizzled source chunk (elements)

  // hoisted per-thread staging pointers (clamps are loop-invariant)
  const unsigned short* pA[4];
  const unsigned short* pB[4];
  #pragma unroll
  for (int p = 0; p < 4; p++) {
    int ra = wid * 32 + p * 8;
    int gr = m0 + ra + lr8; if (gr > M - 1) gr = M - 1;
    pA[p] = A + (long long)gr * lda + sc;
    int gn = n0 + ra + lr8; if (gn > N - 1) gn = N - 1;
    pB[p] = B + (long long)gn * ldb + sc;
  }

  for (int k0 = 0; k0 < K; k0 += 64) {
    #pragma unroll
    for (int p = 0; p < 4; p++) {
      int ra = wid * 32 + p * 8;                   // wave-uniform row base
      gload_lds16(pA[p] + k0, As + ra * 64);
      gload_lds16(pB[p] + k0, Bs + ra * 64);
    }
    __syncthreads();                               // drains vmcnt + converge
    #pragma unroll
    for (int ks = 0; ks < 2; ks++) {
      short8 af[4], bfr[4];
      #pragma unroll
      for (int i = 0; i < 4; i++)
        af[i]  = *(const short8*)(As + (wm * 64 + i * 16 + l16) * 64 + (((ks * 4 + quad) ^ (l16 & 7)) * 8));
      #pragma unroll
      for (int j = 0; j < 4; j++)
        bfr[j] = *(const short8*)(Bs + (wn * 64 + j * 16 + l16) * 64 + (((ks * 4 + quad) ^ (l16 & 7)) * 8));
      #pragma unroll
      for (int i = 0; i < 4; i++)
        #pragma unroll
        for (int j = 0; j < 4; j++)
          acc[i][j] = __builtin_amdgcn_mfma_f32_16x16x32_bf16(af[i], bfr[j], acc[i][j], 0, 0, 0);
    }
    __syncthreads();                               // done reading before next stage
  }

  // -------- epilogue via LDS (per-wave 16x64 fp32 slab, row stride 68) -----
  float* cs = (float*)SMEM + wid * (16 * 68);
  int erow = lane >> 2;
  int eq   = lane & 3;

  #pragma unroll
  for (int i = 0; i < 4; i++) {
    #pragma unroll
    for (int j = 0; j < 4; j++)
      #pragma unroll
      for (int r = 0; r < 4; r++)
        cs[(quad * 4 + r) * 68 + j * 16 + l16] = acc[i][j][r];
    int grow = m0 + wm * 64 + i * 16 + erow;
    bool rowok = grow < M;

    if constexpr (EPI == EPI_BIAS_RES_F32) {
      #pragma unroll
      for (int t = 0; t < 4; t++) {
        int colb = t * 16 + eq * 4;
        int gcol = n0 + wn * 64 + colb;
        if (!rowok || gcol >= N) continue;
        float4 vv = *(const float4*)&cs[erow * 68 + colb];
        float4 bb = *(const float4*)&bias[gcol];
        const float4 rr = *(const float4*)&res[(long long)grow * ldc + gcol];
        vv.x += bb.x + rr.x; vv.y += bb.y + rr.y;
        vv.z += bb.z + rr.z; vv.w += bb.w + rr.w;
        *(float4*)((float*)Cout + (long long)grow * ldc + gcol) = vv;
      }
    } else {
      #pragma unroll
      for (int h = 0; h < 2; h++) {
        int colb = h * 32 + eq * 8;
        int gcol = n0 + wn * 64 + colb;
        if (!rowok || gcol >= N) continue;
        float4 a0 = *(const float4*)&cs[erow * 68 + colb];
        float4 a1 = *(const float4*)&cs[erow * 68 + colb + 4];
        float vs[8] = {a0.x, a0.y, a0.z, a0.w, a1.x, a1.y, a1.z, a1.w};
        if constexpr (EPI == EPI_BIAS_GELU_BF16) {
          float4 b0 = *(const float4*)&bias[gcol];
          float4 b1 = *(const float4*)&bias[gcol + 4];
          float bs[8] = {b0.x, b0.y, b0.z, b0.w, b1.x, b1.y, b1.z, b1.w};
          #pragma unroll
          for (int e = 0; e < 8; e++) {
            float tt = vs[e] + bs[e];
            float ex = __builtin_amdgcn_exp2f(tt * -2.4554669595930156f);
            vs[e] = tt / (1.f + ex);
          }
        }
        union { unsigned short s[8]; uint4 u; } p;
        #pragma unroll
        for (int e = 0; e < 8; e++) p.s[e] = f2bf(vs[e]);
        *(uint4*)((unsigned short*)Cout + (long long)grow * ldc + gcol) = p.u;
      }
    }
  }
}

// ----------------------------------------------------------------------------
extern "C" void kernel_launch(void* const* d_in, const int* in_sizes, int n_in,
                              void* d_out, int out_size, void* d_ws, size_t ws_size,
                              hipStream_t stream) {
  const float* x   = (const float*)d_in[0];
  const float* g1  = (const float*)d_in[1];
  const float* be1 = (const float*)d_in[2];
  const float* Wq  = (const float*)d_in[3];
  const float* Wk  = (const float*)d_in[4];
  const float* Wv  = (const float*)d_in[5];
  const float* Wp  = (const float*)d_in[6];
  const float* bp  = (const float*)d_in[7];
  const float* g2  = (const float*)d_in[8];
  const float* be2 = (const float*)d_in[9];
  const float* W1  = (const float*)d_in[10];
  const float* b1  = (const float*)d_in[11];
  const float* W2  = (const float*)d_in[12];
  const float* b2  = (const float*)d_in[13];
  float* out = (float*)d_out;

  char* ws = (char*)d_ws;
  size_t off = 0;
  auto alloc = [&](size_t bytes) {
    size_t r = off; off += (bytes + 255) & ~(size_t)255; return r;
  };
  unsigned short* wqkv_bf = (unsigned short*)(ws + alloc((size_t)3 * DIM * DIM * 2)); // [Wq;Wk;Wv]
  unsigned short* wp_bf   = (unsigned short*)(ws + alloc((size_t)DIM * DIM * 2));
  unsigned short* w1_bf   = (unsigned short*)(ws + alloc((size_t)HIDDEN * DIM * 2));
  unsigned short* w2_bf   = (unsigned short*)(ws + alloc((size_t)HIDDEN * DIM * 2));
  unsigned short* h_bf    = (unsigned short*)(ws + alloc((size_t)M_ROWS * DIM * 2));  // ln1; later o; later ln2
  unsigned short* qkv_bf  = (unsigned short*)(ws + alloc((size_t)M_ROWS * QKVLD * 2));
  unsigned short* vt_bf   = (unsigned short*)(ws + alloc((size_t)256 * HEAD_DIM * NPAD2 * 2));

  unsigned short* o_bf  = h_bf;     // o written after ln1-out dead
  unsigned short* h2_bf = h_bf;     // ln2-out after o consumed
  unsigned short* u_bf  = qkv_bf;   // MLP hidden (75.6 MB) over dead [qkv|vt] span
  float*          x1    = out;      // residual-1 lives in d_out

  // 1. all weights fp32 -> bf16, one launch
  convert_all_kernel<<<12 * (DIM * DIM / 4) / 256, 256, 0, stream>>>(
      Wq, Wk, Wv, Wp, W1, W2, wqkv_bf, wp_bf, w1_bf, w2_bf);

  // 2. h = LN1(x)
  ln_kernel<<<M_ROWS, 256, 0, stream>>>(x, g1, be1, h_bf);

  // 3. qkv = h @ [Wq;Wk;Wv]^T   (one GEMM, N = 3072)
  gemm_nt<EPI_BF16><<<dim3(73, 24), 256, 0, stream>>>(h_bf, DIM, wqkv_bf, DIM,
      qkv_bf, QKVLD, nullptr, nullptr, M_ROWS, 3 * DIM, DIM);

  // 4. vt[bh][d][n]
  transpose_v_kernel<<<dim3(10, 256), 256, 0, stream>>>(qkv_bf + 2 * DIM, vt_bf);

  // 5. fused flash attention -> o
  flash_attn_kernel<<<dim3(5, 256), 256, 0, stream>>>(
      qkv_bf, qkv_bf + DIM, vt_bf, o_bf);

  // 6. x1 = x + O @ Wp^T + bp   (x1 lives in d_out)
  gemm_nt<EPI_BIAS_RES_F32><<<dim3(73, 8), 256, 0, stream>>>(o_bf, DIM, wp_bf, DIM,
      x1, DIM, bp, x, M_ROWS, DIM, DIM);

  // 7. h2 = LN2(x1)
  ln_kernel<<<M_ROWS, 256, 0, stream>>>(x1, g2, be2, h2_bf);

  // 8. u = fast_gelu(h2 @ W1^T + b1)
  gemm_nt<EPI_BIAS_GELU_BF16><<<dim3(73, 32), 256, 0, stream>>>(h2_bf, DIM, w1_bf, DIM,
      u_bf, HIDDEN, b1, nullptr, M_ROWS, HIDDEN, DIM);

  // 9. out = x1 + u @ W2^T + b2
  gemm_nt<EPI_BIAS_RES_F32><<<dim3(73, 8), 256, 0, stream>>>(u_bf, HIDDEN, w2_bf, HIDDEN,
      out, DIM, b2, x1, M_ROWS, DIM, HIDDEN);
}